// Round 1
// baseline (223.453 us; speedup 1.0000x reference)
//
#include <hip/hip_runtime.h>
#include <math.h>

#define B_DIM 4096
#define D_DIM 4096
#define C_DIM 1000

__global__ __launch_bounds__(256) void adaptive_noise_kernel(
    const float* __restrict__ x,
    const float* __restrict__ model_output,
    const float* __restrict__ rand_u,
    const float* __restrict__ noise_std,
    float* __restrict__ out)
{
    const int b = blockIdx.x;
    const int t = threadIdx.x;

    // ---- Step 1: per-row confidence = 1 / sum(exp(l - max(l))) ----
    // 1000 floats per row = 250 float4; threads 0..249 each load one.
    float4 v;
    v.x = v.y = v.z = v.w = -INFINITY;
    const float4* mo4 = (const float4*)(model_output + (size_t)b * C_DIM);
    if (t < C_DIM / 4) v = mo4[t];

    float lm = fmaxf(fmaxf(v.x, v.y), fmaxf(v.z, v.w));
    // wave (64-lane) max reduce
    #pragma unroll
    for (int off = 32; off > 0; off >>= 1)
        lm = fmaxf(lm, __shfl_down(lm, off, 64));

    __shared__ float red[4];
    const int wave = t >> 6;
    if ((t & 63) == 0) red[wave] = lm;
    __syncthreads();
    const float m = fmaxf(fmaxf(red[0], red[1]), fmaxf(red[2], red[3]));
    __syncthreads();   // before reusing red[]

    float ls = 0.0f;
    if (t < C_DIM / 4) {
        ls = __expf(v.x - m) + __expf(v.y - m) + __expf(v.z - m) + __expf(v.w - m);
    }
    #pragma unroll
    for (int off = 32; off > 0; off >>= 1)
        ls += __shfl_down(ls, off, 64);
    if ((t & 63) == 0) red[wave] = ls;
    __syncthreads();
    const float S = (red[0] + red[1]) + (red[2] + red[3]);
    const float confidence = 1.0f / S;
    const float scale = fminf(0.1f * (1.0f + confidence), 1.0f);

    // ---- Step 2: elementwise masked noise add over this row (4096 floats) ----
    const size_t row = (size_t)b * D_DIM;
    const float4* x4 = (const float4*)(x + row);
    const float4* r4 = (const float4*)(rand_u + row);
    const float4* n4 = (const float4*)(noise_std + row);
    float4*       o4 = (float4*)(out + row);

    #pragma unroll
    for (int i = 0; i < D_DIM / 4 / 256; ++i) {   // 4 iterations
        const int idx = t + i * 256;
        float4 xv = x4[idx];
        float4 rv = r4[idx];
        float4 nv = n4[idx];
        float4 ov;
        ov.x = xv.x + (rv.x < 0.3f ? nv.x * scale : 0.0f);
        ov.y = xv.y + (rv.y < 0.3f ? nv.y * scale : 0.0f);
        ov.z = xv.z + (rv.z < 0.3f ? nv.z * scale : 0.0f);
        ov.w = xv.w + (rv.w < 0.3f ? nv.w * scale : 0.0f);
        o4[idx] = ov;
    }
}

extern "C" void kernel_launch(void* const* d_in, const int* in_sizes, int n_in,
                              void* d_out, int out_size, void* d_ws, size_t ws_size,
                              hipStream_t stream) {
    const float* x            = (const float*)d_in[0];
    const float* model_output = (const float*)d_in[1];
    const float* rand_u       = (const float*)d_in[2];
    const float* noise_std    = (const float*)d_in[3];
    float* out = (float*)d_out;

    adaptive_noise_kernel<<<B_DIM, 256, 0, stream>>>(x, model_output, rand_u, noise_std, out);
}